// Round 6
// baseline (150.374 us; speedup 1.0000x reference)
//
#include <hip/hip_runtime.h>
#include <math.h>

// Problem constants
#define BATCH 8192
#define NFEAT 256
#define NH1   100     // fc1 width (K of fc2)
#define NH2   50      // fc2 width (N of fc2)
#define KP    128     // K padded: 4 MFMA k-steps of 32
#define FPB   8       // features per block (inner loop)
#define RPB   256     // batch rows per block (32 per wave, 8 waves)

typedef __attribute__((ext_vector_type(8))) _Float16 half8;   // MFMA A/B frag
typedef __attribute__((ext_vector_type(2))) _Float16 h2v;     // packed fp16 pair
typedef __attribute__((ext_vector_type(4))) float    float4v; // MFMA acc

// ---- workspace layout (fp32 units from ws start) ----
// w2h : NFEAT*8192 f16 = 4 MB (fragment-ordered, zero-padded)
// w1h/b1h : NFEAT*KP f16 (zero-padded)
#define OFF_W1H  (NFEAT * 8192 / 2)
#define OFF_B1H  (OFF_W1H + NFEAT * KP / 2)

// ---- prep v2 (R16): grid = (4 kk-quarters, NFEAT). Coalesced W2 slice ->
// LDS (stride 40, 2-way aliasing = free) -> coalesced fragment stores.
__global__ __launch_bounds__(256) void prep(
    const float* __restrict__ W1, const float* __restrict__ b1,
    const float* __restrict__ W2, float* __restrict__ ws,
    float* __restrict__ out)
{
    __shared__ float l2[NH2 * 40];       // 8 KB
    const int q = blockIdx.x;            // kk quarter 0..3
    const int f = blockIdx.y;
    const int t = threadIdx.x;

    if (q == 0) {
        _Float16* w1h = (_Float16*)(ws + OFF_W1H) + f * KP;
        _Float16* b1h = (_Float16*)(ws + OFF_B1H) + f * KP;
        if (t < KP) {
            w1h[t] = (_Float16)((t < NH1) ? W1[f * NH1 + t] : 0.f);
            b1h[t] = (_Float16)((t < NH1) ? b1[f * NH1 + t] : 0.f);
        }
        if (t < 32) out[f * 32 + t] = 0.f;
    }

    const float* __restrict__ w2g = W2 + (size_t)f * NH2 * NH1;
#pragma unroll
    for (int i = 0; i < 7; ++i) {
        const int idx = i * 256 + t;
        if (idx < NH2 * 32) {
            const int o = idx >> 5, hh = idx & 31, h = q * 32 + hh;
            l2[o * 40 + hh] = (h < NH1) ? w2g[o * NH1 + h] : 0.f;
        }
    }
    __syncthreads();

    _Float16* w2h = (_Float16*)ws + (size_t)f * 8192 + q * 2048;
#pragma unroll
    for (int i = 0; i < 8; ++i) {
        const int el   = i * 256 + t;          // 0..2047
        const int j    = el & 7;
        const int lane = (el >> 3) & 63;
        const int nt   = (el >> 9) & 3;
        const int o    = nt * 16 + (lane & 15);
        const int hl   = (lane >> 4) * 8 + j;
        w2h[el] = (_Float16)((o < NH2) ? l2[o * 40 + hl] : 0.f);
    }
}

// async 16KB stage for 512-thread block: 2 x (512 lanes x 16B) DMA.
__device__ __forceinline__ void stage_async(
    const _Float16* __restrict__ src, _Float16* dst, int t)
{
#pragma unroll
    for (int i = 0; i < 2; ++i) {
        const _Float16* g = src + (i * 512 + t) * 8;
        _Float16* l       = dst + (i * 512 + t) * 8;
        __builtin_amdgcn_global_load_lds(
            (const __attribute__((address_space(1))) unsigned*)g,
            (__attribute__((address_space(3))) unsigned*)l, 16, 0, 0);
    }
}

// ---- main, R27: exact R22 body (proven 45.5us), ONLY change: launch
// bounds (512,4) -> (512,8) for 4 blocks/CU.
// Evidence chain: R22 busy-times MFMA ~13us + VALU ~19us vs 45.5us wall
// -> ~13us (~30%) unoverlapped stall at the per-feature barrier+vmcnt(0)
// DMA drain (all 8 waves idle together). R23 showed the barrier can't be
// removed (exposed latency costs more); R26 showed in-kernel fencing is
// worse still. Remaining lever: more co-resident blocks so other blocks'
// waves cover the drain (m114 implicit overlap). Budgets: measured
// VGPR_Count=48 <= 64 (the (512,8) budget) and LDS 40960*4 = 163840 B =
// exactly 160 KiB -> 4 blocks/CU fits exactly. (The old "R21 (512,8)
// spilled @80 live" note predates this fp16-x-tile body; 48 measured ->
// re-test. Go/no-go: WRITE_SIZE must stay ~4MB.)
__global__ __launch_bounds__(512, 8) void nam_mfma(
    const float* __restrict__ x,
    const float* __restrict__ ws,
    const float* __restrict__ b2,
    const float* __restrict__ W3,
    float* __restrict__ out)
{
    __shared__ _Float16 lds[2][8192];      // 32 KB: B-fragment double buffer
    __shared__ _Float16 xshh[FPB * RPB];   // 4 KB: x[fi][row] fp16
    __shared__ _Float16 wsh[FPB * KP];     // 2 KB: W1 slices
    __shared__ _Float16 csh[FPB * KP];     // 2 KB: b1 slices

    const int t   = threadIdx.x;
    const int wv  = t >> 6;                // wave 0..7
    const int l64 = t & 63;
    const int ln  = t & 15;
    const int qd  = (t >> 4) & 3;
    const int rowbase = blockIdx.x * RPB + wv * 32;
    const int f0      = blockIdx.y * FPB;

    const _Float16* w2h = (const _Float16*)ws;
    const _Float16* w1h = (const _Float16*)(ws + OFF_W1H);
    const _Float16* b1h = (const _Float16*)(ws + OFF_B1H);

    int osrc[4];
#pragma unroll
    for (int nt = 0; nt < 4; ++nt) {
        const int o = nt * 16 + ln;
        osrc[nt] = (o < NH2) ? o : 0;      // clamped; killed by wo=0
    }

    // ---- one-time staging: B f0 (async) + x tile (fp16 transposed) + w1/b1
    stage_async(w2h + (size_t)f0 * 8192, lds[0], t);
    {
        const int r = t >> 1, half = t & 1;           // 512 thr: 256 rows x 2
        const float4 v = *(const float4*)(
            x + (size_t)(blockIdx.x * RPB + r) * NFEAT + f0 + half * 4);
        xshh[(half * 4 + 0) * RPB + r] = (_Float16)v.x;
        xshh[(half * 4 + 1) * RPB + r] = (_Float16)v.y;
        xshh[(half * 4 + 2) * RPB + r] = (_Float16)v.z;
        xshh[(half * 4 + 3) * RPB + r] = (_Float16)v.w;
    }
    if (t < 128)
        ((int4*)wsh)[t] = ((const int4*)(w1h + (size_t)f0 * KP))[t];
    else if (t < 256)
        ((int4*)csh)[t - 128] = ((const int4*)(b1h + (size_t)f0 * KP))[t - 128];
    __syncthreads();

    float rp[2][4] = {{0.f}, {0.f}};       // contrib, summed over f

#pragma unroll 1
    for (int fi = 0; fi < FPB; ++fi) {
        const int f = f0 + fi;
        const _Float16* B = lds[fi & 1];

        // DMA f+1 into the other buffer; lands by this iter's end barrier
        if (fi + 1 < FPB)
            stage_async(w2h + (size_t)(f + 1) * 8192, lds[(fi + 1) & 1], t);

        // x from LDS: consecutive halfwords, broadcast across quads
        h2v xh[2];
#pragma unroll
        for (int mt = 0; mt < 2; ++mt) {
            const _Float16 xs = xshh[fi * RPB + wv * 32 + mt * 16 + ln];
            xh[mt] = (h2v){xs, xs};
        }

        float4v acc[2][4];
#pragma unroll
        for (int mt = 0; mt < 2; ++mt)
#pragma unroll
            for (int nt = 0; nt < 4; ++nt) acc[mt][nt] = (float4v){0.f, 0.f, 0.f, 0.f};

        const h2v z2 = (h2v){(_Float16)0.f, (_Float16)0.f};

#pragma unroll
        for (int kk = 0; kk < 4; ++kk) {
            half8 bf[4];
#pragma unroll
            for (int nt = 0; nt < 4; ++nt)
                bf[nt] = *(const half8*)(B + (kk * 4 + nt) * 512 + l64 * 8);

            // w1/b1 fragment: one ds_read_b128 each (contiguous 8 f16)
            const half8 wv8 = *(const half8*)(wsh + fi * KP + kk * 32 + qd * 8);
            const half8 cv8 = *(const half8*)(csh + fi * KP + kk * 32 + qd * 8);
            const h2v* wpp = (const h2v*)&wv8;
            const h2v* cpp = (const h2v*)&cv8;

#pragma unroll
            for (int mt = 0; mt < 2; ++mt) {
                half8 af;
                h2v* ap = (h2v*)&af;
                ap[0] = __builtin_elementwise_max(wpp[0] * xh[mt] + cpp[0], z2);
                ap[1] = __builtin_elementwise_max(wpp[1] * xh[mt] + cpp[1], z2);
                ap[2] = __builtin_elementwise_max(wpp[2] * xh[mt] + cpp[2], z2);
                ap[3] = __builtin_elementwise_max(wpp[3] * xh[mt] + cpp[3], z2);
#pragma unroll
                for (int nt = 0; nt < 4; ++nt)
                    acc[mt][nt] = __builtin_amdgcn_mfma_f32_16x16x32_f16(
                        af, bf[nt], acc[mt][nt], 0, 0, 0);
            }
        }

        // epilogue for this f: h2 = relu(acc + b2); rp += h2 * w3
        const float* __restrict__ b2g = b2 + f * NH2;
        const float* __restrict__ w3g = W3 + f * NH2;
#pragma unroll
        for (int nt = 0; nt < 4; ++nt) {
            const int o = nt * 16 + ln;
            const float bo = b2g[osrc[nt]];
            const float wo = (o < NH2) ? w3g[osrc[nt]] : 0.f;
#pragma unroll
            for (int mt = 0; mt < 2; ++mt)
#pragma unroll
                for (int r = 0; r < 4; ++r)
                    rp[mt][r] = fmaf(fmaxf(acc[mt][nt][r] + bo, 0.f), wo, rp[mt][r]);
        }

        __syncthreads();   // drains DMA (f+1 ready) + releases buffer fi&1
    }

    // ---- shuffle-reduce rp over the 16 columns, one atomic per row ----
#pragma unroll
    for (int mt = 0; mt < 2; ++mt)
#pragma unroll
        for (int r = 0; r < 4; ++r) {
            float v = rp[mt][r];
            v += __shfl_xor(v, 1);
            v += __shfl_xor(v, 2);
            v += __shfl_xor(v, 4);
            v += __shfl_xor(v, 8);
            if (ln == 0)
                atomicAdd(out + rowbase + mt * 16 + qd * 4 + r, v);
        }
}

__global__ __launch_bounds__(256) void nam_finish(
    float* __restrict__ out, const float* __restrict__ bias)
{
    const int b = blockIdx.x * blockDim.x + threadIdx.x;
    out[b] = 1.0f / (1.0f + expf(-(out[b] + bias[0])));
}

extern "C" void kernel_launch(void* const* d_in, const int* in_sizes, int n_in,
                              void* d_out, int out_size, void* d_ws, size_t ws_size,
                              hipStream_t stream) {
    const float* x    = (const float*)d_in[0];
    const float* W1   = (const float*)d_in[1];
    const float* b1   = (const float*)d_in[2];
    const float* W2   = (const float*)d_in[3];
    const float* b2   = (const float*)d_in[4];
    const float* W3   = (const float*)d_in[5];
    const float* bias = (const float*)d_in[6];
    float* out = (float*)d_out;
    float* ws  = (float*)d_ws;   // ~4.3 MB used

    prep<<<dim3(4, NFEAT), 256, 0, stream>>>(W1, b1, W2, ws, out);

    nam_mfma<<<dim3(BATCH / RPB, NFEAT / FPB), 512, 0, stream>>>(
        x, ws, b2, W3, out);

    nam_finish<<<BATCH / 256, 256, 0, stream>>>(out, bias);
}

// Round 7
// 118.146 us; speedup vs baseline: 1.2728x; 1.2728x over previous
//
#include <hip/hip_runtime.h>
#include <math.h>

// Problem constants
#define BATCH 8192
#define NFEAT 256
#define NH1   100     // fc1 width (K of fc2)
#define NH2   50      // fc2 width (N of fc2)
#define KP    128     // K padded: 4 MFMA k-steps of 32
#define FPB   8       // features per block (inner loop)
#define RPB   256     // batch rows per block (32 per wave, 8 waves)

typedef __attribute__((ext_vector_type(8))) _Float16 half8;   // MFMA A/B frag
typedef __attribute__((ext_vector_type(2))) _Float16 h2v;     // packed fp16 pair
typedef __attribute__((ext_vector_type(4))) float    float4v; // MFMA acc

// ---- workspace layout (fp32 units from ws start) ----
// w2h : NFEAT*8192 f16 = 4 MB (fragment-ordered, zero-padded)
// w1h/b1h : NFEAT*KP f16 (zero-padded)
#define OFF_W1H  (NFEAT * 8192 / 2)
#define OFF_B1H  (OFF_W1H + NFEAT * KP / 2)

// ---- prep v2 (R16): grid = (4 kk-quarters, NFEAT). Coalesced W2 slice ->
// LDS (stride 40, 2-way aliasing = free) -> coalesced fragment stores.
__global__ __launch_bounds__(256) void prep(
    const float* __restrict__ W1, const float* __restrict__ b1,
    const float* __restrict__ W2, float* __restrict__ ws,
    float* __restrict__ out)
{
    __shared__ float l2[NH2 * 40];       // 8 KB
    const int q = blockIdx.x;            // kk quarter 0..3
    const int f = blockIdx.y;
    const int t = threadIdx.x;

    if (q == 0) {
        _Float16* w1h = (_Float16*)(ws + OFF_W1H) + f * KP;
        _Float16* b1h = (_Float16*)(ws + OFF_B1H) + f * KP;
        if (t < KP) {
            w1h[t] = (_Float16)((t < NH1) ? W1[f * NH1 + t] : 0.f);
            b1h[t] = (_Float16)((t < NH1) ? b1[f * NH1 + t] : 0.f);
        }
        if (t < 32) out[f * 32 + t] = 0.f;
    }

    const float* __restrict__ w2g = W2 + (size_t)f * NH2 * NH1;
#pragma unroll
    for (int i = 0; i < 7; ++i) {
        const int idx = i * 256 + t;
        if (idx < NH2 * 32) {
            const int o = idx >> 5, hh = idx & 31, h = q * 32 + hh;
            l2[o * 40 + hh] = (h < NH1) ? w2g[o * NH1 + h] : 0.f;
        }
    }
    __syncthreads();

    _Float16* w2h = (_Float16*)ws + (size_t)f * 8192 + q * 2048;
#pragma unroll
    for (int i = 0; i < 8; ++i) {
        const int el   = i * 256 + t;          // 0..2047
        const int j    = el & 7;
        const int lane = (el >> 3) & 63;
        const int nt   = (el >> 9) & 3;
        const int o    = nt * 16 + (lane & 15);
        const int hl   = (lane >> 4) * 8 + j;
        w2h[el] = (_Float16)((o < NH2) ? l2[o * 40 + hl] : 0.f);
    }
}

// async 16KB stage for 512-thread block: 2 x (512 lanes x 16B) DMA.
__device__ __forceinline__ void stage_async(
    const _Float16* __restrict__ src, _Float16* dst, int t)
{
#pragma unroll
    for (int i = 0; i < 2; ++i) {
        const _Float16* g = src + (i * 512 + t) * 8;
        _Float16* l       = dst + (i * 512 + t) * 8;
        __builtin_amdgcn_global_load_lds(
            (const __attribute__((address_space(1))) unsigned*)g,
            (__attribute__((address_space(3))) unsigned*)l, 16, 0, 0);
    }
}

// ---- main, R28: R22 per-feature body UNCHANGED; sync structure changed to
// TWO features per barrier with a 4-buffer LDS ring.
// Evidence: R22-R27 pipe busy-times constant (MFMA ~13us, VALU ~19us, LDS
// ~15us) vs 45.5us wall -> phase-serialized convoy: the per-feature barrier
// locksteps all 8 waves (everyone ds_reads together, everyone epilogues
// together) and pays drain+skew 8x/block. R23: barrier can't be removed
// (exposed latency worse). R26: in-kernel fences worse. R27: occupancy
// capped by regs (live=80: 48 arch + 32 acc). Remaining lever: halve the
// barrier COUNT. Iter it handles f=2it,2it+1 from bufs (2it)&3,(2it+1)&3,
// stages f+2,f+3 into the pair freed at the PREVIOUS barrier (race-free),
// one __syncthreads per pair: 4 drains instead of 8, each DMA gets ~2
// compute phases of slack. Cost: LDS 40->72KB (2 blocks/CU max).
__global__ __launch_bounds__(512, 4) void nam_mfma(
    const float* __restrict__ x,
    const float* __restrict__ ws,
    const float* __restrict__ b2,
    const float* __restrict__ W3,
    float* __restrict__ out)
{
    __shared__ _Float16 lds[4][8192];      // 64 KB: B-fragment 4-ring
    __shared__ _Float16 xshh[FPB * RPB];   // 4 KB: x[fi][row] fp16
    __shared__ _Float16 wsh[FPB * KP];     // 2 KB: W1 slices
    __shared__ _Float16 csh[FPB * KP];     // 2 KB: b1 slices

    const int t   = threadIdx.x;
    const int wv  = t >> 6;                // wave 0..7
    const int l64 = t & 63;
    const int ln  = t & 15;
    const int qd  = (t >> 4) & 3;
    const int rowbase = blockIdx.x * RPB + wv * 32;
    const int f0      = blockIdx.y * FPB;

    const _Float16* w2h = (const _Float16*)ws;
    const _Float16* w1h = (const _Float16*)(ws + OFF_W1H);
    const _Float16* b1h = (const _Float16*)(ws + OFF_B1H);

    int osrc[4];
#pragma unroll
    for (int nt = 0; nt < 4; ++nt) {
        const int o = nt * 16 + ln;
        osrc[nt] = (o < NH2) ? o : 0;      // clamped; killed by wo=0
    }

    // ---- one-time staging: B f0,f0+1 (async) + x tile + w1/b1
    stage_async(w2h + (size_t)f0 * 8192, lds[0], t);
    stage_async(w2h + (size_t)(f0 + 1) * 8192, lds[1], t);
    {
        const int r = t >> 1, half = t & 1;           // 512 thr: 256 rows x 2
        const float4 v = *(const float4*)(
            x + (size_t)(blockIdx.x * RPB + r) * NFEAT + f0 + half * 4);
        xshh[(half * 4 + 0) * RPB + r] = (_Float16)v.x;
        xshh[(half * 4 + 1) * RPB + r] = (_Float16)v.y;
        xshh[(half * 4 + 2) * RPB + r] = (_Float16)v.z;
        xshh[(half * 4 + 3) * RPB + r] = (_Float16)v.w;
    }
    if (t < 128)
        ((int4*)wsh)[t] = ((const int4*)(w1h + (size_t)f0 * KP))[t];
    else if (t < 256)
        ((int4*)csh)[t - 128] = ((const int4*)(b1h + (size_t)f0 * KP))[t - 128];
    __syncthreads();

    float rp[2][4] = {{0.f}, {0.f}};       // contrib, summed over f

#pragma unroll 1
    for (int it = 0; it < FPB / 2; ++it) {
        const int fib = 2 * it;

        // stage the NEXT pair into the buffers freed at the previous barrier
        if (it + 1 < FPB / 2) {
            stage_async(w2h + (size_t)(f0 + fib + 2) * 8192, lds[(fib + 2) & 3], t);
            stage_async(w2h + (size_t)(f0 + fib + 3) * 8192, lds[(fib + 3) & 3], t);
        }

#pragma unroll
        for (int s = 0; s < 2; ++s) {
            const int fi = fib + s;
            const int f  = f0 + fi;
            const _Float16* B = lds[fi & 3];

            // x from LDS: consecutive halfwords, broadcast across quads
            h2v xh[2];
#pragma unroll
            for (int mt = 0; mt < 2; ++mt) {
                const _Float16 xs = xshh[fi * RPB + wv * 32 + mt * 16 + ln];
                xh[mt] = (h2v){xs, xs};
            }

            float4v acc[2][4];
#pragma unroll
            for (int mt = 0; mt < 2; ++mt)
#pragma unroll
                for (int nt = 0; nt < 4; ++nt)
                    acc[mt][nt] = (float4v){0.f, 0.f, 0.f, 0.f};

            const h2v z2 = (h2v){(_Float16)0.f, (_Float16)0.f};

#pragma unroll
            for (int kk = 0; kk < 4; ++kk) {
                half8 bf[4];
#pragma unroll
                for (int nt = 0; nt < 4; ++nt)
                    bf[nt] = *(const half8*)(B + (kk * 4 + nt) * 512 + l64 * 8);

                // w1/b1 fragment: one ds_read_b128 each (contiguous 8 f16)
                const half8 wv8 = *(const half8*)(wsh + fi * KP + kk * 32 + qd * 8);
                const half8 cv8 = *(const half8*)(csh + fi * KP + kk * 32 + qd * 8);
                const h2v* wpp = (const h2v*)&wv8;
                const h2v* cpp = (const h2v*)&cv8;

#pragma unroll
                for (int mt = 0; mt < 2; ++mt) {
                    half8 af;
                    h2v* ap = (h2v*)&af;
                    ap[0] = __builtin_elementwise_max(wpp[0] * xh[mt] + cpp[0], z2);
                    ap[1] = __builtin_elementwise_max(wpp[1] * xh[mt] + cpp[1], z2);
                    ap[2] = __builtin_elementwise_max(wpp[2] * xh[mt] + cpp[2], z2);
                    ap[3] = __builtin_elementwise_max(wpp[3] * xh[mt] + cpp[3], z2);
#pragma unroll
                    for (int nt = 0; nt < 4; ++nt)
                        acc[mt][nt] = __builtin_amdgcn_mfma_f32_16x16x32_f16(
                            af, bf[nt], acc[mt][nt], 0, 0, 0);
                }
            }

            // epilogue for this f: h2 = relu(acc + b2); rp += h2 * w3
            const float* __restrict__ b2g = b2 + f * NH2;
            const float* __restrict__ w3g = W3 + f * NH2;
#pragma unroll
            for (int nt = 0; nt < 4; ++nt) {
                const int o = nt * 16 + ln;
                const float bo = b2g[osrc[nt]];
                const float wo = (o < NH2) ? w3g[osrc[nt]] : 0.f;
#pragma unroll
                for (int mt = 0; mt < 2; ++mt)
#pragma unroll
                    for (int r = 0; r < 4; ++r)
                        rp[mt][r] = fmaf(fmaxf(acc[mt][nt][r] + bo, 0.f), wo, rp[mt][r]);
            }
        }

        __syncthreads();   // ONE barrier per 2 features: drains DMA pair,
                           // releases the buffer pair just read
    }

    // ---- shuffle-reduce rp over the 16 columns, one atomic per row ----
#pragma unroll
    for (int mt = 0; mt < 2; ++mt)
#pragma unroll
        for (int r = 0; r < 4; ++r) {
            float v = rp[mt][r];
            v += __shfl_xor(v, 1);
            v += __shfl_xor(v, 2);
            v += __shfl_xor(v, 4);
            v += __shfl_xor(v, 8);
            if (ln == 0)
                atomicAdd(out + rowbase + mt * 16 + qd * 4 + r, v);
        }
}

__global__ __launch_bounds__(256) void nam_finish(
    float* __restrict__ out, const float* __restrict__ bias)
{
    const int b = blockIdx.x * blockDim.x + threadIdx.x;
    out[b] = 1.0f / (1.0f + expf(-(out[b] + bias[0])));
}

extern "C" void kernel_launch(void* const* d_in, const int* in_sizes, int n_in,
                              void* d_out, int out_size, void* d_ws, size_t ws_size,
                              hipStream_t stream) {
    const float* x    = (const float*)d_in[0];
    const float* W1   = (const float*)d_in[1];
    const float* b1   = (const float*)d_in[2];
    const float* W2   = (const float*)d_in[3];
    const float* b2   = (const float*)d_in[4];
    const float* W3   = (const float*)d_in[5];
    const float* bias = (const float*)d_in[6];
    float* out = (float*)d_out;
    float* ws  = (float*)d_ws;   // ~4.3 MB used

    prep<<<dim3(4, NFEAT), 256, 0, stream>>>(W1, b1, W2, ws, out);

    nam_mfma<<<dim3(BATCH / RPB, NFEAT / FPB), 512, 0, stream>>>(
        x, ws, b2, W3, out);

    nam_finish<<<BATCH / 256, 256, 0, stream>>>(out, bias);
}

// Round 8
// 116.996 us; speedup vs baseline: 1.2853x; 1.0098x over previous
//
#include <hip/hip_runtime.h>
#include <math.h>

// Problem constants
#define BATCH 8192
#define NFEAT 256
#define NH1   100     // fc1 width (K of fc2)
#define NH2   50      // fc2 width (N of fc2)
#define KP    128     // K padded: 4 MFMA k-steps of 32
#define FPB   8       // features per block (inner loop)
#define MT    3       // 16-row MFMA tiles per wave (48 rows/wave)
#define RPB   384     // batch rows per block (48 per wave, 8 waves)

typedef __attribute__((ext_vector_type(8))) _Float16 half8;   // MFMA A/B frag
typedef __attribute__((ext_vector_type(2))) _Float16 h2v;     // packed fp16 pair
typedef __attribute__((ext_vector_type(4))) float    float4v; // MFMA acc

// ---- workspace layout (fp32 units from ws start) ----
// w2h : NFEAT*8192 f16 = 4 MB (fragment-ordered, zero-padded)
// w1h/b1h : NFEAT*KP f16 (zero-padded)
#define OFF_W1H  (NFEAT * 8192 / 2)
#define OFF_B1H  (OFF_W1H + NFEAT * KP / 2)

// ---- prep v2 (R16): grid = (4 kk-quarters, NFEAT). Coalesced W2 slice ->
// LDS (stride 40, 2-way aliasing = free) -> coalesced fragment stores.
__global__ __launch_bounds__(256) void prep(
    const float* __restrict__ W1, const float* __restrict__ b1,
    const float* __restrict__ W2, float* __restrict__ ws,
    float* __restrict__ out)
{
    __shared__ float l2[NH2 * 40];       // 8 KB
    const int q = blockIdx.x;            // kk quarter 0..3
    const int f = blockIdx.y;
    const int t = threadIdx.x;

    if (q == 0) {
        _Float16* w1h = (_Float16*)(ws + OFF_W1H) + f * KP;
        _Float16* b1h = (_Float16*)(ws + OFF_B1H) + f * KP;
        if (t < KP) {
            w1h[t] = (_Float16)((t < NH1) ? W1[f * NH1 + t] : 0.f);
            b1h[t] = (_Float16)((t < NH1) ? b1[f * NH1 + t] : 0.f);
        }
        if (t < 32) out[f * 32 + t] = 0.f;
    }

    const float* __restrict__ w2g = W2 + (size_t)f * NH2 * NH1;
#pragma unroll
    for (int i = 0; i < 7; ++i) {
        const int idx = i * 256 + t;
        if (idx < NH2 * 32) {
            const int o = idx >> 5, hh = idx & 31, h = q * 32 + hh;
            l2[o * 40 + hh] = (h < NH1) ? w2g[o * NH1 + h] : 0.f;
        }
    }
    __syncthreads();

    _Float16* w2h = (_Float16*)ws + (size_t)f * 8192 + q * 2048;
#pragma unroll
    for (int i = 0; i < 8; ++i) {
        const int el   = i * 256 + t;          // 0..2047
        const int j    = el & 7;
        const int lane = (el >> 3) & 63;
        const int nt   = (el >> 9) & 3;
        const int o    = nt * 16 + (lane & 15);
        const int hl   = (lane >> 4) * 8 + j;
        w2h[el] = (_Float16)((o < NH2) ? l2[o * 40 + hl] : 0.f);
    }
}

// async 16KB stage for 512-thread block: 2 x (512 lanes x 16B) DMA.
__device__ __forceinline__ void stage_async(
    const _Float16* __restrict__ src, _Float16* dst, int t)
{
#pragma unroll
    for (int i = 0; i < 2; ++i) {
        const _Float16* g = src + (i * 512 + t) * 8;
        _Float16* l       = dst + (i * 512 + t) * 8;
        __builtin_amdgcn_global_load_lds(
            (const __attribute__((address_space(1))) unsigned*)g,
            (__attribute__((address_space(3))) unsigned*)l, 16, 0, 0);
    }
}

// ---- main, R29: R22 body with MT=3 (48 rows/wave) — single-variable.
// Pipe budget from counters (R22, 45.5us): LDS-read ~23us (TOP pipe:
// 1024blk x 8f x 8wv x 24 ds_read_b128 x 1KB = 1.57GB @ 69TB/s), VALU
// 19us, MFMA 12.3us. Barrier structure exonerated (R23 remove=worse,
// R26 fence=worse, R28 halve=neutral: stall is bytes-proportional).
// B-reads (16/24) serve only 32 rows/wave -> rows/wave is THE lever.
// MT=4xNT4 spilled (acc 64); N-split duplicated VALU. MT=3: acc 48,
// live ~110 < 128 budget, B-bytes/row 1.5x down, w1/b1 amortized 1.5x.
// LDS 23 -> ~15.5us. Ragged grid: RPB=384, 22 x-blocks, clamp x-loads,
// guard atomics (+3% padded rows). Go/no-go: WRITE_SIZE must stay ~4MB.
__global__ __launch_bounds__(512, 4) void nam_mfma(
    const float* __restrict__ x,
    const float* __restrict__ ws,
    const float* __restrict__ b2,
    const float* __restrict__ W3,
    float* __restrict__ out)
{
    __shared__ _Float16 lds[2][8192];      // 32 KB: B-fragment double buffer
    __shared__ _Float16 xshh[FPB * RPB];   // 6 KB: x[fi][row] fp16
    __shared__ _Float16 wsh[FPB * KP];     // 2 KB: W1 slices
    __shared__ _Float16 csh[FPB * KP];     // 2 KB: b1 slices

    const int t   = threadIdx.x;
    const int wv  = t >> 6;                // wave 0..7
    const int l64 = t & 63;
    const int ln  = t & 15;
    const int qd  = (t >> 4) & 3;
    const int rowbase = blockIdx.x * RPB + wv * 48;
    const int f0      = blockIdx.y * FPB;

    const _Float16* w2h = (const _Float16*)ws;
    const _Float16* w1h = (const _Float16*)(ws + OFF_W1H);
    const _Float16* b1h = (const _Float16*)(ws + OFF_B1H);

    int osrc[4];
#pragma unroll
    for (int nt = 0; nt < 4; ++nt) {
        const int o = nt * 16 + ln;
        osrc[nt] = (o < NH2) ? o : 0;      // clamped; killed by wo=0
    }

    // ---- one-time staging: B f0 (async) + x tile (fp16 transposed) + w1/b1
    stage_async(w2h + (size_t)f0 * 8192, lds[0], t);
#pragma unroll
    for (int i = 0; i < 2; ++i) {
        const int idx = i * 512 + t;           // 768 tasks: 384 rows x 2
        if (idx < 2 * RPB) {
            const int r = idx >> 1, half = idx & 1;
            int grow = blockIdx.x * RPB + r;
            if (grow >= BATCH) grow = BATCH - 1;   // clamp (guarded at store)
            const float4 v = *(const float4*)(
                x + (size_t)grow * NFEAT + f0 + half * 4);
            xshh[(half * 4 + 0) * RPB + r] = (_Float16)v.x;
            xshh[(half * 4 + 1) * RPB + r] = (_Float16)v.y;
            xshh[(half * 4 + 2) * RPB + r] = (_Float16)v.z;
            xshh[(half * 4 + 3) * RPB + r] = (_Float16)v.w;
        }
    }
    if (t < 128)
        ((int4*)wsh)[t] = ((const int4*)(w1h + (size_t)f0 * KP))[t];
    else if (t < 256)
        ((int4*)csh)[t - 128] = ((const int4*)(b1h + (size_t)f0 * KP))[t - 128];
    __syncthreads();

    float rp[MT][4] = {{0.f}, {0.f}, {0.f}};   // contrib, summed over f

#pragma unroll 1
    for (int fi = 0; fi < FPB; ++fi) {
        const int f = f0 + fi;
        const _Float16* B = lds[fi & 1];

        // DMA f+1 into the other buffer; lands by this iter's end barrier
        if (fi + 1 < FPB)
            stage_async(w2h + (size_t)(f + 1) * 8192, lds[(fi + 1) & 1], t);

        // x from LDS: consecutive halfwords, broadcast across quads
        h2v xh[MT];
#pragma unroll
        for (int mt = 0; mt < MT; ++mt) {
            const _Float16 xs = xshh[fi * RPB + wv * 48 + mt * 16 + ln];
            xh[mt] = (h2v){xs, xs};
        }

        float4v acc[MT][4];
#pragma unroll
        for (int mt = 0; mt < MT; ++mt)
#pragma unroll
            for (int nt = 0; nt < 4; ++nt)
                acc[mt][nt] = (float4v){0.f, 0.f, 0.f, 0.f};

        const h2v z2 = (h2v){(_Float16)0.f, (_Float16)0.f};

#pragma unroll
        for (int kk = 0; kk < 4; ++kk) {
            half8 bf[4];
#pragma unroll
            for (int nt = 0; nt < 4; ++nt)
                bf[nt] = *(const half8*)(B + (kk * 4 + nt) * 512 + l64 * 8);

            // w1/b1 fragment: one ds_read_b128 each (contiguous 8 f16)
            const half8 wv8 = *(const half8*)(wsh + fi * KP + kk * 32 + qd * 8);
            const half8 cv8 = *(const half8*)(csh + fi * KP + kk * 32 + qd * 8);
            const h2v* wpp = (const h2v*)&wv8;
            const h2v* cpp = (const h2v*)&cv8;

#pragma unroll
            for (int mt = 0; mt < MT; ++mt) {
                half8 af;
                h2v* ap = (h2v*)&af;
                ap[0] = __builtin_elementwise_max(wpp[0] * xh[mt] + cpp[0], z2);
                ap[1] = __builtin_elementwise_max(wpp[1] * xh[mt] + cpp[1], z2);
                ap[2] = __builtin_elementwise_max(wpp[2] * xh[mt] + cpp[2], z2);
                ap[3] = __builtin_elementwise_max(wpp[3] * xh[mt] + cpp[3], z2);
#pragma unroll
                for (int nt = 0; nt < 4; ++nt)
                    acc[mt][nt] = __builtin_amdgcn_mfma_f32_16x16x32_f16(
                        af, bf[nt], acc[mt][nt], 0, 0, 0);
            }
        }

        // epilogue for this f: h2 = relu(acc + b2); rp += h2 * w3
        const float* __restrict__ b2g = b2 + f * NH2;
        const float* __restrict__ w3g = W3 + f * NH2;
#pragma unroll
        for (int nt = 0; nt < 4; ++nt) {
            const int o = nt * 16 + ln;
            const float bo = b2g[osrc[nt]];
            const float wo = (o < NH2) ? w3g[osrc[nt]] : 0.f;
#pragma unroll
            for (int mt = 0; mt < MT; ++mt)
#pragma unroll
                for (int r = 0; r < 4; ++r)
                    rp[mt][r] = fmaf(fmaxf(acc[mt][nt][r] + bo, 0.f), wo, rp[mt][r]);
        }

        __syncthreads();   // drains DMA (f+1 ready) + releases buffer fi&1
    }

    // ---- shuffle-reduce rp over the 16 columns, one atomic per row ----
#pragma unroll
    for (int mt = 0; mt < MT; ++mt)
#pragma unroll
        for (int r = 0; r < 4; ++r) {
            float v = rp[mt][r];
            v += __shfl_xor(v, 1);
            v += __shfl_xor(v, 2);
            v += __shfl_xor(v, 4);
            v += __shfl_xor(v, 8);
            const int row = rowbase + mt * 16 + qd * 4 + r;
            if (ln == 0 && row < BATCH)
                atomicAdd(out + row, v);
        }
}

__global__ __launch_bounds__(256) void nam_finish(
    float* __restrict__ out, const float* __restrict__ bias)
{
    const int b = blockIdx.x * blockDim.x + threadIdx.x;
    out[b] = 1.0f / (1.0f + expf(-(out[b] + bias[0])));
}

extern "C" void kernel_launch(void* const* d_in, const int* in_sizes, int n_in,
                              void* d_out, int out_size, void* d_ws, size_t ws_size,
                              hipStream_t stream) {
    const float* x    = (const float*)d_in[0];
    const float* W1   = (const float*)d_in[1];
    const float* b1   = (const float*)d_in[2];
    const float* W2   = (const float*)d_in[3];
    const float* b2   = (const float*)d_in[4];
    const float* W3   = (const float*)d_in[5];
    const float* bias = (const float*)d_in[6];
    float* out = (float*)d_out;
    float* ws  = (float*)d_ws;   // ~4.3 MB used

    prep<<<dim3(4, NFEAT), 256, 0, stream>>>(W1, b1, W2, ws, out);

    nam_mfma<<<dim3((BATCH + RPB - 1) / RPB, NFEAT / FPB), 512, 0, stream>>>(
        x, ws, b2, W3, out);

    nam_finish<<<BATCH / 256, 256, 0, stream>>>(out, bias);
}